// Round 5
// baseline (1010.632 us; speedup 1.0000x reference)
//
#include <hip/hip_runtime.h>
#include <math.h>

// ---- problem constants ----
#define HW 65536
#define WP 129
#define NPOS 33024          // 256*129
#define NHALF 16512         // NPOS/2
#define MMAX 16257          // max m value + 1 (127*128+1)
#define PI_F 3.14159265358979f

// skewed LDS index: every FFT access set maps to <=2 lanes/bank (free)
#define ZX(i) ((i) + ((i)>>5))

__device__ __forceinline__ int rev7(int x){ return (int)(__brev((unsigned)x) >> 25); }
__device__ __forceinline__ int rev8(int x){ return (int)(__brev((unsigned)x) >> 24); }

// wave-local LDS fence: drain all LDS ops of this wave + block compiler reordering.
// Valid because each wave's FFT touches only its own Z row (no cross-wave data).
__device__ __forceinline__ void wsync() {
  asm volatile("s_waitcnt lgkmcnt(0)" ::: "memory");
}

// stage-packed twiddle fill: tab[L+kk] = exp(sgn*i*pi*kk/L), L=pow2, kk in [0,L]
// (index 256 = L=128,kk=128). Contiguous per-stage reads -> conflict-free.
template<int SGN>
__device__ __forceinline__ void fill_tab(float* tc, float* ts, int tid) {
  if (tid >= 1 && tid <= 256) {
    int L = 1 << (31 - __clz(tid));
    if (tid == 256) L = 128;
    int kk = tid - L;
    float sn, cs; sincosf(SGN * PI_F * kk / L, &sn, &cs);
    tc[tid] = cs; ts[tid] = sn;
  }
}

// ---------------- permutation maps (counting sort over m = mu(i)*j) --------------
__global__ void k_hist(int* __restrict__ hist) {
  int v = blockIdx.x*256 + threadIdx.x;
  if (v >= MMAX) return;
  int cnt;
  if (v == 0) cnt = 512;  // row0(129) + j=0 rows 1..254 (254) + row255(129)
  else {
    cnt = 0;
    for (int d = 1; d <= 127; ++d)
      if (v % d == 0 && v / d <= 128) cnt += 2;   // rows i=d and i=255-d
  }
  hist[v] = cnt;
}

__global__ void k_scan(const int* __restrict__ hist, int* __restrict__ base) {
  __shared__ int part[512];
  int t = threadIdx.x;
  int lo = t*32, hi = lo+32; if (hi > MMAX) hi = MMAX;
  int s = 0;
  if (lo < MMAX) for (int i = lo; i < hi; ++i) s += hist[i];
  part[t] = s;
  __syncthreads();
  for (int off = 1; off < 512; off <<= 1) {
    int v = (t >= off) ? part[t-off] : 0;
    __syncthreads();
    part[t] += v;
    __syncthreads();
  }
  int acc = part[t] - s;  // exclusive
  if (lo < MMAX) for (int i = lo; i < hi; ++i) { base[i] = acc; acc += hist[i]; }
}

__global__ void k_build(const int* __restrict__ base, int* __restrict__ idx, int* __restrict__ inv) {
  int v = blockIdx.x*256 + threadIdx.x;
  if (v >= MMAX) return;
  int s = base[v];
  if (v == 0) {
    for (int j = 0; j < 129; ++j) { idx[s] = j; inv[j] = s; ++s; }
    for (int i = 1; i < 255; ++i) { int p = i*129; idx[s] = p; inv[p] = s; ++s; }
    for (int j = 0; j < 129; ++j) { int p = 255*129 + j; idx[s] = p; inv[p] = s; ++s; }
  } else {
    for (int i = 1; i < 255; ++i) {
      int d = (i < 128) ? i : 255 - i;
      if (v % d == 0) {
        int j = v / d;
        if (j <= 128) { int p = i*129 + j; idx[s] = p; inv[p] = s; ++s; }
      }
    }
  }
}

// t-space: t = k*256 + h  (transposed natural layout)
__global__ void k_maps(const int* __restrict__ idx, const int* __restrict__ inv,
                       int* __restrict__ partner_t, int* __restrict__ half_t) {
  int t = blockIdx.x*256 + threadIdx.x;
  if (t >= NPOS) return;
  int k = t >> 8, h = t & 255;
  int p = h*129 + k;
  int s = inv[p];
  int f = (s >= NHALF) ? 1 : 0;
  int s2 = f ? (s - NHALF) : (s + NHALF);
  int pp = idx[s2];
  int kk = pp % 129, hh = pp / 129;
  partner_t[t] = kk*256 + hh;
  half_t[t] = f;
}

// sorted column n -> t-space position of half0/half1 element of that column
__global__ void k_maps2(const int* __restrict__ idx,
                        int* __restrict__ t0n, int* __restrict__ t1n) {
  int n = blockIdx.x*256 + threadIdx.x;
  if (n >= NHALF) return;
  int p0 = idx[n], p1 = idx[n + NHALF];
  t0n[n] = (p0 % 129)*256 + p0/129;
  t1n[n] = (p1 % 129)*256 + p1/129;
}

__global__ void k_zero(float* __restrict__ g) {
  int i = blockIdx.x*256 + threadIdx.x;
  if (i < 34816) g[i] = 0.f;   // gram(32768) + nq(1024) + nk(1024)
}

// ---------------- 64->64 pointwise conv, GEMM-tiled ------------------------------
// tile: 64 outch x 256 px; thread tile 8 outch x (4+4) px (stride-16B LDS reads);
// register-staged prefetch overlaps next chunk's HBM latency with FMA phase.
__global__ __launch_bounds__(256) void k_conv64(const float* __restrict__ in,
        const float* __restrict__ w, float* __restrict__ outp) {
  __shared__ float wT[64][65];    // wT[c][o], +1 pad
  __shared__ float xs[16][260];   // xs[c][px], +4 pad
  int tid = threadIdx.x;
  int ti = tid >> 5, tj = tid & 31;
  int lb = blockIdx.y;
  int px0 = blockIdx.x * 256;
  const float* ib = in + (size_t)lb*64*HW + px0;
  for (int e = tid; e < 4096; e += 256) { int o = e >> 6, c = e & 63; wT[c][o] = w[e]; }
  // prologue: chunk 0 into registers
  float4 rbuf[4];
  #pragma unroll
  for (int q = 0; q < 4; ++q) {
    int e = q*256 + tid;
    int c = e >> 6, p4 = (e & 63) << 2;
    rbuf[q] = *(const float4*)(ib + (size_t)c*HW + p4);
  }
  float acc[64];
  #pragma unroll
  for (int z = 0; z < 64; ++z) acc[z] = 0.f;
  for (int cc = 0; cc < 4; ++cc) {
    __syncthreads();   // prev compute done (xs free); wT ready on first iter
    #pragma unroll
    for (int q = 0; q < 4; ++q) {
      int e = q*256 + tid;
      int c = e >> 6, p4 = (e & 63) << 2;
      *(float4*)&xs[c][p4] = rbuf[q];
    }
    if (cc < 3) {     // issue next chunk's loads; latency hides under compute
      #pragma unroll
      for (int q = 0; q < 4; ++q) {
        int e = q*256 + tid;
        int c = e >> 6, p4 = (e & 63) << 2;
        rbuf[q] = *(const float4*)(ib + (size_t)((cc+1)*16 + c)*HW + p4);
      }
    }
    __syncthreads();
    #pragma unroll
    for (int k = 0; k < 16; ++k) {
      float wv[8], xv[8];
      *(float4*)&wv[0] = *(const float4*)&wT[cc*16+k][ti*8];
      *(float4*)&wv[4] = *(const float4*)&wT[cc*16+k][ti*8+4];
      *(float4*)&xv[0] = *(const float4*)&xs[k][tj*4];          // stride-16B: conflict-free
      *(float4*)&xv[4] = *(const float4*)&xs[k][128 + tj*4];
      #pragma unroll
      for (int o = 0; o < 8; ++o) {
        #pragma unroll
        for (int p = 0; p < 8; ++p)
          acc[o*8+p] += wv[o]*xv[p];
      }
    }
  }
  float* ob = outp + (size_t)lb*64*HW + px0;
  #pragma unroll
  for (int o = 0; o < 8; ++o) {
    *(float4*)(ob + (size_t)(ti*8+o)*HW + tj*4)       = *(float4*)&acc[o*8];
    *(float4*)(ob + (size_t)(ti*8+o)*HW + 128 + tj*4) = *(float4*)&acc[o*8+4];
  }
}

// ------- fused depthwise3x3 + row rfft (256 real -> 129 cplx), t-layout store ----
// float2 rows (b64 reads), stage-packed twiddles, skewed Z
__global__ __launch_bounds__(512) void k_dwrowfft(const float* __restrict__ tmp,
        const float* __restrict__ wdw, float* __restrict__ planes,
        int tensor, size_t psz) {
  __shared__ float2 rows2[10][130];
  __shared__ float Zr[8][132], Zi[8][132];
  __shared__ float Xr[8][132], Xi[8][132];
  __shared__ float tc[258], ts[258];
  int tid = threadIdx.x;
  int wave = tid >> 6, lane = tid & 63;
  int lb = blockIdx.z, c = blockIdx.y;
  int h0 = blockIdx.x * 8;
  fill_tab<-1>(tc, ts, tid);
  const float* ib = tmp + ((size_t)lb*64 + c)*HW;
  for (int e = tid; e < 1280; e += 512) {
    int r = e >> 7, p = e & 127;
    int y = h0 - 1 + r;
    rows2[r][p] = (y >= 0 && y < 256) ? *(const float2*)(ib + y*256 + 2*p)
                                      : make_float2(0.f, 0.f);
  }
  const float* w9 = wdw + ((size_t)tensor*64 + c)*9;
  float w0=w9[0],w1=w9[1],w2=w9[2],w3=w9[3],w4=w9[4],w5=w9[5],w6=w9[6],w7=w9[7],w8=w9[8];
  __syncthreads();   // publish rows + twiddle table
  float d[4];
  #pragma unroll
  for (int g = 0; g < 2; ++g) {
    int lp = g*64 + lane;
    float a0 = 0.f, a1 = 0.f;   // outputs at cols 2lp, 2lp+1
    #pragma unroll
    for (int r = 0; r < 3; ++r) {
      float2 pm = (lp > 0)   ? rows2[wave+r][lp-1] : make_float2(0.f,0.f);
      float2 p0 = rows2[wave+r][lp];
      float2 pp = (lp < 127) ? rows2[wave+r][lp+1] : make_float2(0.f,0.f);
      float wl = (r==0)?w0:((r==1)?w3:w6);
      float wm = (r==0)?w1:((r==1)?w4:w7);
      float wr = (r==0)?w2:((r==1)?w5:w8);
      a0 += pm.y*wl + p0.x*wm + p0.y*wr;
      a1 += p0.x*wl + p0.y*wm + pp.x*wr;
    }
    d[2*g] = a0; d[2*g+1] = a1;
  }
  int r0 = rev7(lane), r1 = rev7(lane+64);
  Zr[wave][ZX(r0)] = d[0]; Zi[wave][ZX(r0)] = d[1];
  Zr[wave][ZX(r1)] = d[2]; Zi[wave][ZX(r1)] = d[3];
  wsync();
  #pragma unroll
  for (int s = 0; s < 7; ++s) {
    int L = 1 << s;
    int kk = lane & (L-1);
    int i0 = ((lane ^ kk) << 1) | kk;
    float cs = tc[L+kk], sn = ts[L+kk];
    int a = ZX(i0), b2 = ZX(i0+L);
    float ur = Zr[wave][a],  ui = Zi[wave][a];
    float ar = Zr[wave][b2], ai = Zi[wave][b2];
    float tr = ar*cs - ai*sn;
    float ti = ar*sn + ai*cs;
    Zr[wave][a]  = ur+tr; Zi[wave][a]  = ui+ti;
    Zr[wave][b2] = ur-tr; Zi[wave][b2] = ui-ti;
    wsync();
  }
  for (int kk = lane; kk <= 128; kk += 64) {
    int a = ZX(kk & 127), bb = ZX((128-kk) & 127);
    float Zkr = Zr[wave][a],  Zki = Zi[wave][a];
    float Zmr = Zr[wave][bb], Zmi = Zi[wave][bb];
    float Er = 0.5f*(Zkr + Zmr), Ei = 0.5f*(Zki - Zmi);
    float Or = 0.5f*(Zki + Zmi), Oi = 0.5f*(Zmr - Zkr);
    float cs = tc[128+kk], sn = ts[128+kk];
    Xr[wave][kk] = (Er + cs*Or - sn*Oi)*(1.0f/256.0f);
    Xi[wave][kk] = (Ei + cs*Oi + sn*Or)*(1.0f/256.0f);
  }
  __syncthreads();   // publish X across waves (transposed store)
  float* pre = planes + (size_t)(tensor*2)*psz + ((size_t)lb*64 + c)*NPOS;
  float* pim = pre + psz;
  for (int e = tid; e < 1032; e += 512) {
    int k = e >> 3, hh = e & 7;
    pre[(size_t)k*256 + h0 + hh] = Xr[hh][k];
    pim[(size_t)k*256 + h0 + hh] = Xi[hh][k];
  }
}

// ---------------- column FFT: 256-pt complex, in-place on planes -----------------
__global__ __launch_bounds__(512) void k_colfft(float* __restrict__ planes,
        int tensor, size_t psz) {
  __shared__ float Zr[8][264], Zi[8][264];
  __shared__ float tc[258], ts[258];
  int tid = threadIdx.x;
  int wave = tid >> 6, lane = tid & 63;
  int lb = blockIdx.z, c = blockIdx.y;
  int kreal = blockIdx.x*8 + wave;
  int k = (kreal < 129) ? kreal : 128;
  fill_tab<-1>(tc, ts, tid);
  float* pre = planes + (size_t)(tensor*2)*psz + ((size_t)lb*64 + c)*NPOS + (size_t)k*256;
  float* pim = pre + psz;
  #pragma unroll
  for (int i = 0; i < 4; ++i) {
    int h = lane + 64*i;
    int r = ZX(rev8(h));
    Zr[wave][r] = pre[h]; Zi[wave][r] = pim[h];
  }
  __syncthreads();   // publish table (dup k=128 waves compute garbage, never store)
  #pragma unroll
  for (int s = 0; s < 8; ++s) {
    int L = 1 << s;
    #pragma unroll
    for (int jj = 0; jj < 2; ++jj) {
      int j = lane + 64*jj;
      int kk = j & (L-1);
      int i0 = ((j ^ kk) << 1) | kk;
      float cs = tc[L+kk], sn = ts[L+kk];
      int a = ZX(i0), b2 = ZX(i0+L);
      float ur = Zr[wave][a],  ui = Zi[wave][a];
      float ar = Zr[wave][b2], ai = Zi[wave][b2];
      float tr = ar*cs - ai*sn;
      float ti = ar*sn + ai*cs;
      Zr[wave][a]  = ur+tr; Zi[wave][a]  = ui+ti;
      Zr[wave][b2] = ur-tr; Zi[wave][b2] = ui-ti;
    }
    wsync();
  }
  if (kreal <= 128) {
    #pragma unroll
    for (int i = 0; i < 4; ++i) {
      int h = lane + 64*i;
      pre[h] = Zr[wave][ZX(h)];
      pim[h] = Zi[wave][ZX(h)];
    }
  }
}

// ======== per-(tensor,head) transpose [16ch][NPOS] -> [NPOS][16ch] ===============
__global__ __launch_bounds__(256) void k_t16(const float* __restrict__ P,
        float* __restrict__ T, const int* __restrict__ half_t,
        float* __restrict__ nq, float* __restrict__ nk, int b, size_t psz) {
  __shared__ float ld[256][18];
  int tn = blockIdx.y >> 3, h = blockIdx.y & 7;
  int t0 = blockIdx.x * 256;
  const float* src = P + (size_t)(tn*2 + (h>>2))*psz + ((size_t)(b*64 + (h&3)*16))*NPOS;
  int cr = threadIdx.x >> 4, ts = threadIdx.x & 15;
  float s0 = 0.f, s1 = 0.f;
  #pragma unroll
  for (int p2 = 0; p2 < 16; ++p2) {
    int tt = ts + p2*16;
    float v = src[(size_t)cr*NPOS + t0 + tt];
    ld[tt][cr] = v;
    if (tn < 2) { if (half_t[t0+tt]) s1 += v*v; else s0 += v*v; }
  }
  if (tn < 2) {
    s0 += __shfl_down(s0, 8, 16); s1 += __shfl_down(s1, 8, 16);
    s0 += __shfl_down(s0, 4, 16); s1 += __shfl_down(s1, 4, 16);
    s0 += __shfl_down(s0, 2, 16); s1 += __shfl_down(s1, 2, 16);
    s0 += __shfl_down(s0, 1, 16); s1 += __shfl_down(s1, 1, 16);
    if (ts == 0) {
      float* dn = (tn == 0) ? nq : nk;
      int bh = b*8 + h;
      atomicAdd(&dn[bh*32 + 2*cr],     s0);
      atomicAdd(&dn[bh*32 + 2*cr + 1], s1);
    }
  }
  __syncthreads();
  float* dst = T + ((size_t)blockIdx.y*NPOS + t0)*16;
  int cc = threadIdx.x & 15, tr = threadIdx.x >> 4;
  #pragma unroll
  for (int p2 = 0; p2 < 16; ++p2) {
    int tt = tr + p2*16;
    dst[(size_t)tt*16 + cc] = ld[tt][cc];
  }
}

// ======== gram over sorted columns n, branch-free 4x4 register tiles =============
__global__ __launch_bounds__(256) void k_gramn(const float* __restrict__ T,
        const int* __restrict__ t0n, const int* __restrict__ t1n,
        float* __restrict__ gram, int b) {
  __shared__ float q0s[16][68], q1s[16][68], k0s[16][68], k1s[16][68];
  __shared__ int tl[128];
  __shared__ float red[3][64][16];
  int tid = threadIdx.x;
  int np = tid >> 6, lane = tid & 63;
  int i = lane >> 3, j = lane & 7;
  int h = blockIdx.y;
  const float* Tq = T + (size_t)h*NPOS*16;
  const float* Tk = T + (size_t)(8 + h)*NPOS*16;
  float acc[16];
  #pragma unroll
  for (int z = 0; z < 16; ++z) acc[z] = 0.f;
  for (int it = 0; it < 3; ++it) {
    int n0 = (blockIdx.x*3 + it)*64;
    __syncthreads();
    if (tid < 128) tl[tid] = ((tid < 64) ? t0n[n0 + tid] : t1n[n0 + tid - 64]) * 16;
    __syncthreads();
    for (int e = tid; e < 1024; e += 256) {
      int nn = e >> 4, c2 = e & 15;
      int a0 = tl[nn], a1 = tl[64+nn];
      q0s[c2][nn] = Tq[(size_t)a0 + c2];
      q1s[c2][nn] = Tq[(size_t)a1 + c2];
      k0s[c2][nn] = Tk[(size_t)a0 + c2];
      k1s[c2][nn] = Tk[(size_t)a1 + c2];
    }
    __syncthreads();
    #pragma unroll
    for (int m = 0; m < 4; ++m) {
      int n = m*16 + np*4;
      float4 qA0 = *(const float4*)&q0s[i][n];
      float4 qB0 = *(const float4*)&q0s[i+8][n];
      float4 qA1 = *(const float4*)&q1s[i][n];
      float4 qB1 = *(const float4*)&q1s[i+8][n];
      float4 kA0 = *(const float4*)&k0s[j][n];
      float4 kB0 = *(const float4*)&k0s[j+8][n];
      float4 kA1 = *(const float4*)&k1s[j][n];
      float4 kB1 = *(const float4*)&k1s[j+8][n];
      const float* xa0 = (const float*)&qA0;
      const float* xa1 = (const float*)&qA1;
      const float* xb0 = (const float*)&qB0;
      const float* xb1 = (const float*)&qB1;
      const float* ya0 = (const float*)&kA0;
      const float* ya1 = (const float*)&kA1;
      const float* yb0 = (const float*)&kB0;
      const float* yb1 = (const float*)&kB1;
      #pragma unroll
      for (int nn = 0; nn < 4; ++nn) {
        float xA0 = xa0[nn], xA1 = xa1[nn], xB0 = xb0[nn], xB1 = xb1[nn];
        float yA0 = ya0[nn], yA1 = ya1[nn], yB0 = yb0[nn], yB1 = yb1[nn];
        acc[0]  += xA0*yA0; acc[1]  += xA0*yA1; acc[2]  += xA0*yB0; acc[3]  += xA0*yB1;
        acc[4]  += xA1*yA0; acc[5]  += xA1*yA1; acc[6]  += xA1*yB0; acc[7]  += xA1*yB1;
        acc[8]  += xB0*yA0; acc[9]  += xB0*yA1; acc[10] += xB0*yB0; acc[11] += xB0*yB1;
        acc[12] += xB1*yA0; acc[13] += xB1*yA1; acc[14] += xB1*yB0; acc[15] += xB1*yB1;
      }
    }
  }
  __syncthreads();
  if (np > 0) {
    #pragma unroll
    for (int z = 0; z < 16; ++z) red[np-1][lane][z] = acc[z];
  }
  __syncthreads();
  if (np == 0) {
    float* G = gram + (size_t)(b*8 + h)*1024;
    #pragma unroll
    for (int z = 0; z < 16; ++z) {
      float v = acc[z] + red[0][lane][z] + red[1][lane][z] + red[2][lane][z];
      int qs = z >> 2, ks = z & 3;
      int r  = 2*(i + 8*(qs>>1)) + (qs&1);
      int cl = 2*(j + 8*(ks>>1)) + (ks&1);
      atomicAdd(&G[r*32 + cl], v);
    }
  }
}

// ---------------- softmax1 with cosine normalization + temperature ---------------
__global__ void k_attn(const float* __restrict__ gram, const float* __restrict__ nq,
                       const float* __restrict__ nk, const float* __restrict__ temp,
                       float* __restrict__ attn, int b0) {
  __shared__ float lnk[32];
  int bh = b0*8 + blockIdx.x, h = bh & 7;
  int r = threadIdx.x;
  if (r < 32) lnk[r] = fmaxf(sqrtf(nk[bh*32 + r]), 1e-12f);
  __syncthreads();
  if (r >= 32) return;
  float T = temp[h];
  float nqr = fmaxf(sqrtf(nq[bh*32 + r]), 1e-12f);
  float e[32]; float s = 0.f;
  #pragma unroll
  for (int c = 0; c < 32; ++c) {
    float g = gram[(size_t)bh*1024 + r*32 + c] / (nqr * lnk[c]) * T;
    e[c] = expf(g);
    s += e[c];
  }
  float is = 1.0f / (s + 1.0f);
  #pragma unroll
  for (int c = 0; c < 32; ++c) attn[(size_t)bh*1024 + r*32 + c] = e[c] * is;
}

// ======== O = attn @ V reading transposed Tv (64B lines for t and pt) ============
__global__ __launch_bounds__(256) void k_on(const float* __restrict__ T,
    const float* __restrict__ attn, const int* __restrict__ partner_t,
    const int* __restrict__ half_t, float* __restrict__ O, int b, size_t psz) {
  __shared__ float At[1024];
  int hh = blockIdx.y;
  for (int e = threadIdx.x; e < 1024; e += 256)
    At[e] = attn[(size_t)(b*8 + hh)*1024 + e];
  __syncthreads();
  int t = blockIdx.x*256 + threadIdx.x;
  int f = half_t[t], pt = partner_t[t];
  const float* tv = T + (size_t)(16 + hh)*NPOS*16;
  const float4* va4 = (const float4*)(tv + (size_t)t*16);
  const float4* vb4 = (const float4*)(tv + (size_t)pt*16);
  float w0[16], w1[16];
  #pragma unroll
  for (int dq = 0; dq < 4; ++dq) {
    float4 a = va4[dq], bb = vb4[dq];
    w0[4*dq+0] = f ? bb.x : a.x;  w1[4*dq+0] = f ? a.x : bb.x;
    w0[4*dq+1] = f ? bb.y : a.y;  w1[4*dq+1] = f ? a.y : bb.y;
    w0[4*dq+2] = f ? bb.z : a.z;  w1[4*dq+2] = f ? a.z : bb.z;
    w0[4*dq+3] = f ? bb.w : a.w;  w1[4*dq+3] = f ? a.w : bb.w;
  }
  float* op = O + (size_t)(hh>=4 ? 1:0)*psz + ((size_t)(b*64 + (hh&3)*16))*NPOS;
  #pragma unroll
  for (int c = 0; c < 16; ++c) {
    const float4* Ar = (const float4*)&At[(2*c+f)*32];
    float acc = 0.f;
    #pragma unroll
    for (int d = 0; d < 8; ++d) {
      float4 a4 = Ar[d];
      acc += a4.x*w0[2*d] + a4.y*w1[2*d] + a4.z*w0[2*d+1] + a4.w*w1[2*d+1];
    }
    op[(size_t)c*NPOS + t] = acc;
  }
}

// ---------------- OLD gram + row norms (fallback path, NB<4) ---------------------
__global__ __launch_bounds__(256) void k_gram(const float* __restrict__ planes,
    const int* __restrict__ partner_t, const int* __restrict__ half_t,
    float* __restrict__ gram, float* __restrict__ nq, float* __restrict__ nk,
    int b0, size_t psz) {
  __shared__ float qa[16][65], ka[16][65], kb[16][65];
  __shared__ int ptn[64];
  __shared__ int hf[64];
  int lb = blockIdx.y >> 3, h = blockIdx.y & 7;
  int bh = (b0 + lb)*8 + h;
  const float* qp = planes + (size_t)(h>=4 ? 1:0)*psz + ((size_t)(lb*64 + (h&3)*16))*NPOS;
  const float* kp = planes + (size_t)(2 + (h>=4 ? 1:0))*psz + ((size_t)(lb*64 + (h&3)*16))*NPOS;
  int tc = threadIdx.x & 15, td = threadIdx.x >> 4;
  float a00=0.f,a01=0.f,a10=0.f,a11=0.f, q0=0.f,q1=0.f,k0a=0.f,k1a=0.f;
  for (int it = 0; it < 6; ++it) {
    int t0 = (blockIdx.x*6 + it)*64;
    if (threadIdx.x < 64) {
      ptn[threadIdx.x] = partner_t[t0 + threadIdx.x];
      hf[threadIdx.x]  = half_t[t0 + threadIdx.x];
    }
    __syncthreads();
    for (int e = threadIdx.x; e < 1024; e += 256) {
      int cc = e >> 6, j = e & 63;
      qa[cc][j] = qp[(size_t)cc*NPOS + t0 + j];
      ka[cc][j] = kp[(size_t)cc*NPOS + t0 + j];
      kb[cc][j] = kp[(size_t)cc*NPOS + ptn[j]];
    }
    __syncthreads();
    #pragma unroll 4
    for (int j = 0; j < 64; ++j) {
      float q = qa[tc][j], v1 = ka[td][j], v2 = kb[td][j];
      int f = hf[j];
      float p1 = q*v1, p2 = q*v2;
      if (f) { a11 += p1; a10 += p2; } else { a00 += p1; a01 += p2; }
      if (td == 0) { float qq = q*q; if (f) q1 += qq; else q0 += qq; }
      if (tc == 0) { float kk = v1*v1; if (f) k1a += kk; else k0a += kk; }
    }
    __syncthreads();
  }
  float* G = gram + (size_t)bh*1024;
  atomicAdd(&G[(2*tc+0)*32 + 2*td+0], a00);
  atomicAdd(&G[(2*tc+0)*32 + 2*td+1], a01);
  atomicAdd(&G[(2*tc+1)*32 + 2*td+0], a10);
  atomicAdd(&G[(2*tc+1)*32 + 2*td+1], a11);
  if (td == 0) { atomicAdd(&nq[bh*32 + 2*tc], q0); atomicAdd(&nq[bh*32 + 2*tc+1], q1); }
  if (tc == 0) { atomicAdd(&nk[bh*32 + 2*td], k0a); atomicAdd(&nk[bh*32 + 2*td+1], k1a); }
}

// ---------------- OLD O = attn @ V (fallback path, NB<4) -------------------------
__global__ __launch_bounds__(256) void k_o(const float* __restrict__ planes,
    const float* __restrict__ attn, const int* __restrict__ partner_t,
    const int* __restrict__ half_t, float* __restrict__ O, int b0, size_t psz) {
  __shared__ float At[8][1024];
  int lb = blockIdx.y;
  for (int e = threadIdx.x; e < 8192; e += 256)
    At[e>>10][e&1023] = attn[((size_t)(b0+lb)*8)*1024 + e];
  __syncthreads();
  int t = blockIdx.x*256 + threadIdx.x;
  int f = half_t[t], pt = partner_t[t];
  #pragma unroll 1
  for (int hh = 0; hh < 8; ++hh) {
    const float* vp = planes + (size_t)(4 + (hh>=4 ? 1:0))*psz + ((size_t)(lb*64 + (hh&3)*16))*NPOS;
    float* op = O + (size_t)(hh>=4 ? 1:0)*psz + ((size_t)(lb*64 + (hh&3)*16))*NPOS;
    float w0[16], w1[16];
    #pragma unroll
    for (int d = 0; d < 16; ++d) {
      float va = vp[(size_t)d*NPOS + t];
      float vb = vp[(size_t)d*NPOS + pt];
      w0[d] = f ? vb : va;
      w1[d] = f ? va : vb;
    }
    #pragma unroll
    for (int c = 0; c < 16; ++c) {
      const float4* Ar = (const float4*)&At[hh][(2*c+f)*32];
      float acc = 0.f;
      #pragma unroll
      for (int d = 0; d < 8; ++d) {
        float4 a4 = Ar[d];
        acc += a4.x*w0[2*d] + a4.y*w1[2*d] + a4.z*w0[2*d+1] + a4.w*w1[2*d+1];
      }
      op[(size_t)c*NPOS + t] = acc;
    }
  }
}

// ---------------- inverse column FFT (e^{+}), transpose store, 1/256 -------------
__global__ __launch_bounds__(512) void k_colifft(const float* __restrict__ O,
        float2* __restrict__ IT, size_t psz) {
  __shared__ float Zr[8][264], Zi[8][264];
  __shared__ float tc[258], ts[258];
  int tid = threadIdx.x;
  int wave = tid >> 6, lane = tid & 63;
  int lb = blockIdx.z, c = blockIdx.y;
  int kreal = blockIdx.x*8 + wave;
  int k = (kreal < 129) ? kreal : 128;
  fill_tab<1>(tc, ts, tid);
  const float* pre = O + ((size_t)lb*64 + c)*NPOS + (size_t)k*256;
  const float* pim = pre + psz;
  #pragma unroll
  for (int i = 0; i < 4; ++i) {
    int h = lane + 64*i;
    int r = ZX(rev8(h));
    Zr[wave][r] = pre[h]; Zi[wave][r] = pim[h];
  }
  __syncthreads();   // publish table
  #pragma unroll
  for (int s = 0; s < 8; ++s) {
    int L = 1 << s;
    #pragma unroll
    for (int jj = 0; jj < 2; ++jj) {
      int j = lane + 64*jj;
      int kk = j & (L-1);
      int i0 = ((j ^ kk) << 1) | kk;
      float cs = tc[L+kk], sn = ts[L+kk];
      int a = ZX(i0), b2 = ZX(i0+L);
      float ur = Zr[wave][a],  ui = Zi[wave][a];
      float ar = Zr[wave][b2], ai = Zi[wave][b2];
      float tr = ar*cs - ai*sn;
      float ti = ar*sn + ai*cs;
      Zr[wave][a]  = ur+tr; Zi[wave][a]  = ui+ti;
      Zr[wave][b2] = ur-tr; Zi[wave][b2] = ui-ti;
    }
    wsync();
  }
  __syncthreads();   // publish Z across waves (transposed store reads other waves)
  float2* outp = IT + ((size_t)lb*64 + c)*256*WP;
  int k0 = blockIdx.x*8;
  for (int e = tid; e < 2048; e += 512) {
    int hpos = e >> 3, kk2 = e & 7;
    if (k0 + kk2 <= 128) {
      int a = ZX(hpos);
      outp[(size_t)hpos*WP + k0 + kk2] =
        make_float2(Zr[kk2][a]*(1.0f/256.0f), Zi[kk2][a]*(1.0f/256.0f));
    }
  }
}

// ---------------- row irfft: 129 complex -> 256 real ----------------------------
__global__ __launch_bounds__(512) void k_rowirfft(const float2* __restrict__ IT,
        float* __restrict__ sp) {
  __shared__ float2 Xl[8][132];
  __shared__ float Zr[8][132], Zi[8][132];
  __shared__ float tc[258], ts[258];
  int tid = threadIdx.x;
  int wave = tid >> 6, lane = tid & 63;
  int lb = blockIdx.z, c = blockIdx.y;
  int h = blockIdx.x*8 + wave;
  fill_tab<1>(tc, ts, tid);
  const float2* row = IT + (((size_t)lb*64 + c)*256 + h)*WP;
  float2 v0 = row[lane];     if (lane == 0) v0.y = 0.f;       // imag of DC dropped
  float2 v1 = row[lane+64];
  Xl[wave][lane] = v0;
  Xl[wave][lane+64] = v1;
  if (lane == 0) { float2 vn = row[128]; vn.y = 0.f; Xl[wave][128] = vn; } // Nyquist
  __syncthreads();   // publish table (Xl is wave-local)
  #pragma unroll
  for (int u = 0; u < 2; ++u) {
    int kk = lane + 64*u;
    float2 Xk = Xl[wave][kk];
    float2 Xm = Xl[wave][128-kk];
    float Ar = Xk.x + Xm.x, Ai = Xk.y - Xm.y;   // X[k]+conj(X[128-k])
    float Br = Xk.x - Xm.x, Bi = Xk.y + Xm.y;   // X[k]-conj(X[128-k])
    float cs = tc[128+kk], sn = ts[128+kk];
    float tr = cs*Br - sn*Bi, ti = cs*Bi + sn*Br;  // e^{+2pi i k/256} * B
    int r = ZX(rev7(kk));
    Zr[wave][r] = Ar - ti; Zi[wave][r] = Ai + tr;
  }
  wsync();
  #pragma unroll
  for (int s = 0; s < 7; ++s) {
    int L = 1 << s;
    int kk = lane & (L-1);
    int i0 = ((lane ^ kk) << 1) | kk;
    float cs = tc[L+kk], sn = ts[L+kk];
    int a = ZX(i0), b2 = ZX(i0+L);
    float ur = Zr[wave][a],  ui = Zi[wave][a];
    float ar = Zr[wave][b2], ai = Zi[wave][b2];
    float tr = ar*cs - ai*sn;
    float ti = ar*sn + ai*cs;
    Zr[wave][a]  = ur+tr; Zi[wave][a]  = ui+ti;
    Zr[wave][b2] = ur-tr; Zi[wave][b2] = ui-ti;
    wsync();
  }
  float2* orow = (float2*)(sp + (((size_t)lb*64 + c)*256 + h)*256);
  orow[lane]    = make_float2(Zr[wave][ZX(lane)],    Zi[wave][ZX(lane)]);
  orow[lane+64] = make_float2(Zr[wave][ZX(lane+64)], Zi[wave][ZX(lane+64)]);
}

// =================================================================================
extern "C" void kernel_launch(void* const* d_in, const int* in_sizes, int n_in,
                              void* d_out, int out_size, void* d_ws, size_t ws_size,
                              hipStream_t stream) {
  const float* x      = (const float*)d_in[0];
  const float* w_qkv  = (const float*)d_in[1];
  const float* w_dw   = (const float*)d_in[2];
  const float* w_proj = (const float*)d_in[3];
  const float* temp   = (const float*)d_in[4];
  float* out = (float*)d_out;

  char* ws = (char*)d_ws;
  // SMALL region layout (hist/base dead after k_build; t0n/t1n alias them)
  int*   hist = (int*)(ws + 0);        // 65536 B
  int*   base = (int*)(ws + 65536);    // 65536 B
  int*   t0n  = (int*)(ws + 0);        // 66048 B (aliases hist)
  int*   t1n  = (int*)(ws + 66048);    // 66048 B (aliases hist/base tail)
  int*   idx  = (int*)(ws + 132352);   // 132096 B
  int*   inv  = (int*)(ws + 264448);   // 132096 B
  int*   ptn  = (int*)(ws + 396544);   // 132096 B
  int*   hlf  = (int*)(ws + 528640);   // 132096 B
  float* gram = (float*)(ws + 660736); // 131072 B
  float* nq   = (float*)(ws + 791808); // 4096 B
  float* nk   = (float*)(ws + 795904); // 4096 B
  float* attn = (float*)(ws + 800000); // 131072 B -> ends 931072 < 1 MiB

  const size_t SMALL   = 1048576;
  const size_t PLANESB = 50724864;   // 6 * 64 * 33024 * 4 bytes per batch elem
  int NB = 1;
  if (ws_size >= SMALL + 2*PLANESB) NB = 2;
  if (ws_size >= SMALL + 4*PLANESB) NB = 4;

  float*  P   = (float*)(ws + SMALL);
  size_t  psz = (size_t)NB * 64 * NPOS;   // one plane, in floats
  float*  O   = P;                        // aliases planes 0,1 (Q, dead after gram/t16)
  float2* IT  = (float2*)(P + 2*psz);     // aliases planes 2,3 (K, dead after gram)
  float*  sp  = P + 4*psz;                // aliases planes 4,5 (V, dead after k_o/t16)

  // permutation maps (recomputed every call; ws is re-poisoned by harness)
  k_hist <<<dim3(64), dim3(256), 0, stream>>>(hist);
  k_scan <<<dim3(1),  dim3(512), 0, stream>>>(hist, base);
  k_build<<<dim3(64), dim3(256), 0, stream>>>(base, idx, inv);
  k_maps <<<dim3(129),dim3(256), 0, stream>>>(idx, inv, ptn, hlf);
  k_maps2<<<dim3(65), dim3(256), 0, stream>>>(idx, t0n, t1n);   // overwrites hist/base (dead)
  k_zero <<<dim3(136),dim3(256), 0, stream>>>(gram);

  if (NB == 4) {
    // ---- fast path: single pass, attention uses d_out as transpose scratch ----
    float* tmpb = out;   // staging; dead after forward
    for (int tn = 0; tn < 3; ++tn) {
      k_conv64  <<<dim3(256, 4), dim3(256), 0, stream>>>(x, w_qkv + (size_t)tn*64*64, tmpb);
      k_dwrowfft<<<dim3(32, 64, 4), dim3(512), 0, stream>>>(tmpb, w_dw, P, tn, psz);
      k_colfft  <<<dim3(17, 64, 4), dim3(512), 0, stream>>>(P, tn, psz);
    }
    float* T = out;   // 3 tensors * 8 heads * NPOS * 16 floats = 50.7 MB <= out (67.1 MB)
    for (int b = 0; b < 4; ++b) {
      k_t16  <<<dim3(129, 24), dim3(256), 0, stream>>>(P, T, hlf, nq, nk, b, psz);
      k_gramn<<<dim3(86, 8),   dim3(256), 0, stream>>>(T, t0n, t1n, gram, b);
      k_attn <<<dim3(8),       dim3(64),  0, stream>>>(gram, nq, nk, temp, attn, b);
      k_on   <<<dim3(129, 8),  dim3(256), 0, stream>>>(T, attn, ptn, hlf, O, b, psz);
    }
    k_colifft <<<dim3(17, 64, 4), dim3(512), 0, stream>>>(O, IT, psz);
    k_rowirfft<<<dim3(32, 64, 4), dim3(512), 0, stream>>>(IT, sp);
    k_conv64  <<<dim3(256, 4), dim3(256), 0, stream>>>(sp, w_proj, out);
  } else {
    // ---- fallback: previous verified path ----
    for (int b0 = 0; b0 < 4; b0 += NB) {
      float* tmpb = out + (size_t)b0*64*HW;
      for (int tn = 0; tn < 3; ++tn) {
        k_conv64  <<<dim3(256, NB), dim3(256), 0, stream>>>(
            x + (size_t)b0*64*HW, w_qkv + (size_t)tn*64*64, tmpb);
        k_dwrowfft<<<dim3(32, 64, NB), dim3(512), 0, stream>>>(tmpb, w_dw, P, tn, psz);
        k_colfft  <<<dim3(17, 64, NB), dim3(512), 0, stream>>>(P, tn, psz);
      }
      k_gram<<<dim3(86, NB*8), dim3(256), 0, stream>>>(P, ptn, hlf, gram, nq, nk, b0, psz);
      k_attn<<<dim3(NB*8), dim3(64), 0, stream>>>(gram, nq, nk, temp, attn, b0);
      k_o   <<<dim3(129, NB), dim3(256), 0, stream>>>(P, attn, ptn, hlf, O, b0, psz);
      k_colifft <<<dim3(17, 64, NB), dim3(512), 0, stream>>>(O, IT, psz);
      k_rowirfft<<<dim3(32, 64, NB), dim3(512), 0, stream>>>(IT, sp);
      k_conv64  <<<dim3(256, NB), dim3(256), 0, stream>>>(sp, w_proj, out + (size_t)b0*64*HW);
    }
  }
}

// Round 6
// 966.676 us; speedup vs baseline: 1.0455x; 1.0455x over previous
//
#include <hip/hip_runtime.h>
#include <math.h>

// ---- problem constants ----
#define HW 65536
#define WP 129
#define NPOS 33024          // 256*129
#define NHALF 16512         // NPOS/2
#define MMAX 16257          // max m value + 1 (127*128+1)
#define PI_F 3.14159265358979f

// skewed LDS index: every FFT access set maps to <=2 lanes/bank (free)
#define ZX(i) ((i) + ((i)>>5))

__device__ __forceinline__ int rev7(int x){ return (int)(__brev((unsigned)x) >> 25); }
__device__ __forceinline__ int rev8(int x){ return (int)(__brev((unsigned)x) >> 24); }

// wave-local LDS fence: drain all LDS ops of this wave + block compiler reordering.
__device__ __forceinline__ void wsync() {
  asm volatile("s_waitcnt lgkmcnt(0)" ::: "memory");
}

// stage-packed twiddle fill: tab[L+kk] = exp(sgn*i*pi*kk/L), L=pow2, kk in [0,L]
// (index 256 = L=128,kk=128). Contiguous per-stage reads -> conflict-free.
template<int SGN>
__device__ __forceinline__ void fill_tab(float* tc, float* ts, int tid) {
  if (tid >= 1 && tid <= 256) {
    int L = 1 << (31 - __clz(tid));
    if (tid == 256) L = 128;
    int kk = tid - L;
    float sn, cs; sincosf(SGN * PI_F * kk / L, &sn, &cs);
    tc[tid] = cs; ts[tid] = sn;
  }
}

// register butterfly via shfl_xor: this lane holds position p (bit L of p = `low`).
// Identical arithmetic to the LDS version: tw = w*Z[i0+L]; Z[i0]+tw / Z[i0]-tw.
__device__ __forceinline__ void bf_shfl(float& zr, float& zi, int L, bool low,
                                        float cs, float sn) {
  float pr = __shfl_xor(zr, L);
  float pi = __shfl_xor(zi, L);
  float ur = low ? pr : zr, ui = low ? pi : zi;     // Z[i0]
  float tr = low ? zr : pr, ti = low ? zi : pi;     // Z[i0+L]
  float twr = tr*cs - ti*sn, twi = tr*sn + ti*cs;
  zr = low ? ur - twr : ur + twr;
  zi = low ? ui - twi : ui + twi;
}

// in-thread butterfly: (u, l) -> (u + w*l, u - w*l)
__device__ __forceinline__ void bf_pair(float& ur, float& ui, float& lr, float& li,
                                        float cs, float sn) {
  float twr = lr*cs - li*sn, twi = lr*sn + li*cs;
  lr = ur - twr; li = ui - twi;
  ur = ur + twr; ui = ui + twi;
}

// ---------------- permutation maps (counting sort over m = mu(i)*j) --------------
__global__ void k_hist(int* __restrict__ hist) {
  int v = blockIdx.x*256 + threadIdx.x;
  if (v >= MMAX) return;
  int cnt;
  if (v == 0) cnt = 512;  // row0(129) + j=0 rows 1..254 (254) + row255(129)
  else {
    cnt = 0;
    for (int d = 1; d <= 127; ++d)
      if (v % d == 0 && v / d <= 128) cnt += 2;   // rows i=d and i=255-d
  }
  hist[v] = cnt;
}

__global__ void k_scan(const int* __restrict__ hist, int* __restrict__ base) {
  __shared__ int part[512];
  int t = threadIdx.x;
  int lo = t*32, hi = lo+32; if (hi > MMAX) hi = MMAX;
  int s = 0;
  if (lo < MMAX) for (int i = lo; i < hi; ++i) s += hist[i];
  part[t] = s;
  __syncthreads();
  for (int off = 1; off < 512; off <<= 1) {
    int v = (t >= off) ? part[t-off] : 0;
    __syncthreads();
    part[t] += v;
    __syncthreads();
  }
  int acc = part[t] - s;  // exclusive
  if (lo < MMAX) for (int i = lo; i < hi; ++i) { base[i] = acc; acc += hist[i]; }
}

__global__ void k_build(const int* __restrict__ base, int* __restrict__ idx, int* __restrict__ inv) {
  int v = blockIdx.x*256 + threadIdx.x;
  if (v >= MMAX) return;
  int s = base[v];
  if (v == 0) {
    for (int j = 0; j < 129; ++j) { idx[s] = j; inv[j] = s; ++s; }
    for (int i = 1; i < 255; ++i) { int p = i*129; idx[s] = p; inv[p] = s; ++s; }
    for (int j = 0; j < 129; ++j) { int p = 255*129 + j; idx[s] = p; inv[p] = s; ++s; }
  } else {
    for (int i = 1; i < 255; ++i) {
      int d = (i < 128) ? i : 255 - i;
      if (v % d == 0) {
        int j = v / d;
        if (j <= 128) { int p = i*129 + j; idx[s] = p; inv[p] = s; ++s; }
      }
    }
  }
}

// t-space: t = k*256 + h  (transposed natural layout)
__global__ void k_maps(const int* __restrict__ idx, const int* __restrict__ inv,
                       int* __restrict__ partner_t, int* __restrict__ half_t) {
  int t = blockIdx.x*256 + threadIdx.x;
  if (t >= NPOS) return;
  int k = t >> 8, h = t & 255;
  int p = h*129 + k;
  int s = inv[p];
  int f = (s >= NHALF) ? 1 : 0;
  int s2 = f ? (s - NHALF) : (s + NHALF);
  int pp = idx[s2];
  int kk = pp % 129, hh = pp / 129;
  partner_t[t] = kk*256 + hh;
  half_t[t] = f;
}

// sorted column n -> t-space position of half0/half1 element of that column
__global__ void k_maps2(const int* __restrict__ idx,
                        int* __restrict__ t0n, int* __restrict__ t1n) {
  int n = blockIdx.x*256 + threadIdx.x;
  if (n >= NHALF) return;
  int p0 = idx[n], p1 = idx[n + NHALF];
  t0n[n] = (p0 % 129)*256 + p0/129;
  t1n[n] = (p1 % 129)*256 + p1/129;
}

__global__ void k_zero(float* __restrict__ g) {
  int i = blockIdx.x*256 + threadIdx.x;
  if (i < 34816) g[i] = 0.f;   // gram(32768) + nq(1024) + nk(1024)
}

// ---------------- 64->64 pointwise conv, GEMM-tiled ------------------------------
__global__ __launch_bounds__(256) void k_conv64(const float* __restrict__ in,
        const float* __restrict__ w, float* __restrict__ outp) {
  __shared__ float wT[64][65];    // wT[c][o], +1 pad
  __shared__ float xs[16][260];   // xs[c][px], +4 pad
  int tid = threadIdx.x;
  int ti = tid >> 5, tj = tid & 31;
  int lb = blockIdx.y;
  int px0 = blockIdx.x * 256;
  const float* ib = in + (size_t)lb*64*HW + px0;
  for (int e = tid; e < 4096; e += 256) { int o = e >> 6, c = e & 63; wT[c][o] = w[e]; }
  // prologue: chunk 0 into registers
  float4 rbuf[4];
  #pragma unroll
  for (int q = 0; q < 4; ++q) {
    int e = q*256 + tid;
    int c = e >> 6, p4 = (e & 63) << 2;
    rbuf[q] = *(const float4*)(ib + (size_t)c*HW + p4);
  }
  float acc[64];
  #pragma unroll
  for (int z = 0; z < 64; ++z) acc[z] = 0.f;
  for (int cc = 0; cc < 4; ++cc) {
    __syncthreads();   // prev compute done (xs free); wT ready on first iter
    #pragma unroll
    for (int q = 0; q < 4; ++q) {
      int e = q*256 + tid;
      int c = e >> 6, p4 = (e & 63) << 2;
      *(float4*)&xs[c][p4] = rbuf[q];
    }
    if (cc < 3) {     // issue next chunk's loads; latency hides under compute
      #pragma unroll
      for (int q = 0; q < 4; ++q) {
        int e = q*256 + tid;
        int c = e >> 6, p4 = (e & 63) << 2;
        rbuf[q] = *(const float4*)(ib + (size_t)((cc+1)*16 + c)*HW + p4);
      }
    }
    __syncthreads();
    #pragma unroll
    for (int k = 0; k < 16; ++k) {
      float wv[8], xv[8];
      *(float4*)&wv[0] = *(const float4*)&wT[cc*16+k][ti*8];
      *(float4*)&wv[4] = *(const float4*)&wT[cc*16+k][ti*8+4];
      *(float4*)&xv[0] = *(const float4*)&xs[k][tj*4];          // stride-16B: conflict-free
      *(float4*)&xv[4] = *(const float4*)&xs[k][128 + tj*4];
      #pragma unroll
      for (int o = 0; o < 8; ++o) {
        #pragma unroll
        for (int p = 0; p < 8; ++p)
          acc[o*8+p] += wv[o]*xv[p];
      }
    }
  }
  float* ob = outp + (size_t)lb*64*HW + px0;
  #pragma unroll
  for (int o = 0; o < 8; ++o) {
    *(float4*)(ob + (size_t)(ti*8+o)*HW + tj*4)       = *(float4*)&acc[o*8];
    *(float4*)(ob + (size_t)(ti*8+o)*HW + 128 + tj*4) = *(float4*)&acc[o*8+4];
  }
}

// ------- fused depthwise3x3 + row rfft (256 real -> 129 cplx), t-layout store ----
// register-resident 128-pt FFT via shfl_xor; LDS only for bit-rev redistribute + combine
__global__ __launch_bounds__(512) void k_dwrowfft(const float* __restrict__ tmp,
        const float* __restrict__ wdw, float* __restrict__ planes,
        int tensor, size_t psz) {
  __shared__ float2 rows2[10][130];
  __shared__ float Zr[8][132], Zi[8][132];
  __shared__ float Xr[8][132], Xi[8][132];
  __shared__ float tc[258], ts[258];
  int tid = threadIdx.x;
  int wave = tid >> 6, lane = tid & 63;
  int lb = blockIdx.z, c = blockIdx.y;
  int h0 = blockIdx.x * 8;
  fill_tab<-1>(tc, ts, tid);
  const float* ib = tmp + ((size_t)lb*64 + c)*HW;
  for (int e = tid; e < 1280; e += 512) {
    int r = e >> 7, p = e & 127;
    int y = h0 - 1 + r;
    rows2[r][p] = (y >= 0 && y < 256) ? *(const float2*)(ib + y*256 + 2*p)
                                      : make_float2(0.f, 0.f);
  }
  const float* w9 = wdw + ((size_t)tensor*64 + c)*9;
  float w0=w9[0],w1=w9[1],w2=w9[2],w3=w9[3],w4=w9[4],w5=w9[5],w6=w9[6],w7=w9[7],w8=w9[8];
  __syncthreads();   // publish rows + twiddle table
  float d[4];
  #pragma unroll
  for (int g = 0; g < 2; ++g) {
    int lp = g*64 + lane;
    float a0 = 0.f, a1 = 0.f;   // outputs at cols 2lp, 2lp+1
    #pragma unroll
    for (int r = 0; r < 3; ++r) {
      float2 pm = (lp > 0)   ? rows2[wave+r][lp-1] : make_float2(0.f,0.f);
      float2 p0 = rows2[wave+r][lp];
      float2 pp = (lp < 127) ? rows2[wave+r][lp+1] : make_float2(0.f,0.f);
      float wl = (r==0)?w0:((r==1)?w3:w6);
      float wm = (r==0)?w1:((r==1)?w4:w7);
      float wr = (r==0)?w2:((r==1)?w5:w8);
      a0 += pm.y*wl + p0.x*wm + p0.y*wr;
      a1 += p0.x*wl + p0.y*wm + pp.x*wr;
    }
    d[2*g] = a0; d[2*g+1] = a1;
  }
  // bit-rev redistribute through LDS (wave-private), then FFT in registers
  int r0 = rev7(lane), r1 = rev7(lane+64);
  Zr[wave][ZX(r0)] = d[0]; Zi[wave][ZX(r0)] = d[1];
  Zr[wave][ZX(r1)] = d[2]; Zi[wave][ZX(r1)] = d[3];
  wsync();
  float z0r = Zr[wave][ZX(lane)],    z0i = Zi[wave][ZX(lane)];
  float z1r = Zr[wave][ZX(lane+64)], z1i = Zi[wave][ZX(lane+64)];
  #pragma unroll
  for (int s = 0; s < 6; ++s) {     // L = 1..32: shfl_xor stages
    int L = 1 << s;
    int kk = lane & (L-1);
    float cs = tc[L+kk], sn = ts[L+kk];
    bool low = (lane & L) != 0;
    bf_shfl(z0r, z0i, L, low, cs, sn);
    bf_shfl(z1r, z1i, L, low, cs, sn);
  }
  bf_pair(z0r, z0i, z1r, z1i, tc[64+lane], ts[64+lane]);   // L=64 in-thread
  Zr[wave][ZX(lane)]    = z0r; Zi[wave][ZX(lane)]    = z0i;
  Zr[wave][ZX(lane+64)] = z1r; Zi[wave][ZX(lane+64)] = z1i;
  wsync();
  for (int kk = lane; kk <= 128; kk += 64) {
    int a = ZX(kk & 127), bb = ZX((128-kk) & 127);
    float Zkr = Zr[wave][a],  Zki = Zi[wave][a];
    float Zmr = Zr[wave][bb], Zmi = Zi[wave][bb];
    float Er = 0.5f*(Zkr + Zmr), Ei = 0.5f*(Zki - Zmi);
    float Or = 0.5f*(Zki + Zmi), Oi = 0.5f*(Zmr - Zkr);
    float cs = tc[128+kk], sn = ts[128+kk];
    Xr[wave][kk] = (Er + cs*Or - sn*Oi)*(1.0f/256.0f);
    Xi[wave][kk] = (Ei + cs*Oi + sn*Or)*(1.0f/256.0f);
  }
  __syncthreads();   // publish X across waves (transposed store)
  float* pre = planes + (size_t)(tensor*2)*psz + ((size_t)lb*64 + c)*NPOS;
  float* pim = pre + psz;
  for (int e = tid; e < 1032; e += 512) {
    int k = e >> 3, hh = e & 7;
    pre[(size_t)k*256 + h0 + hh] = Xr[hh][k];
    pim[(size_t)k*256 + h0 + hh] = Xi[hh][k];
  }
}

// ---------------- column FFT: 256-pt complex, in-place, register-resident --------
__global__ __launch_bounds__(512) void k_colfft(float* __restrict__ planes,
        int tensor, size_t psz) {
  __shared__ float Zr[8][264], Zi[8][264];
  __shared__ float tc[258], ts[258];
  int tid = threadIdx.x;
  int wave = tid >> 6, lane = tid & 63;
  int lb = blockIdx.z, c = blockIdx.y;
  int kreal = blockIdx.x*8 + wave;
  int k = (kreal < 129) ? kreal : 128;
  fill_tab<-1>(tc, ts, tid);
  float* pre = planes + (size_t)(tensor*2)*psz + ((size_t)lb*64 + c)*NPOS + (size_t)k*256;
  float* pim = pre + psz;
  #pragma unroll
  for (int i = 0; i < 4; ++i) {
    int h = lane + 64*i;
    int r = ZX(rev8(h));
    Zr[wave][r] = pre[h]; Zi[wave][r] = pim[h];
  }
  __syncthreads();   // publish table (covers wave-private Z too)
  float zr[4], zi[4];
  #pragma unroll
  for (int q = 0; q < 4; ++q) {
    zr[q] = Zr[wave][ZX(lane+64*q)]; zi[q] = Zi[wave][ZX(lane+64*q)];
  }
  #pragma unroll
  for (int s = 0; s < 6; ++s) {     // L = 1..32
    int L = 1 << s;
    int kk = lane & (L-1);
    float cs = tc[L+kk], sn = ts[L+kk];
    bool low = (lane & L) != 0;
    bf_shfl(zr[0], zi[0], L, low, cs, sn);
    bf_shfl(zr[1], zi[1], L, low, cs, sn);
    bf_shfl(zr[2], zi[2], L, low, cs, sn);
    bf_shfl(zr[3], zi[3], L, low, cs, sn);
  }
  { float cs = tc[64+lane], sn = ts[64+lane];     // L=64 in-thread
    bf_pair(zr[0], zi[0], zr[1], zi[1], cs, sn);
    bf_pair(zr[2], zi[2], zr[3], zi[3], cs, sn); }
  bf_pair(zr[0], zi[0], zr[2], zi[2], tc[128+lane], ts[128+lane]);   // L=128
  bf_pair(zr[1], zi[1], zr[3], zi[3], tc[192+lane], ts[192+lane]);
  if (kreal <= 128) {
    #pragma unroll
    for (int q = 0; q < 4; ++q) {
      pre[lane+64*q] = zr[q];
      pim[lane+64*q] = zi[q];
    }
  }
}

// ======== per-(tensor,head) transpose [16ch][NPOS] -> [NPOS][16ch] ===============
__global__ __launch_bounds__(256) void k_t16(const float* __restrict__ P,
        float* __restrict__ T, const int* __restrict__ half_t,
        float* __restrict__ nq, float* __restrict__ nk, int b, size_t psz) {
  __shared__ float ld[256][18];
  int tn = blockIdx.y >> 3, h = blockIdx.y & 7;
  int t0 = blockIdx.x * 256;
  const float* src = P + (size_t)(tn*2 + (h>>2))*psz + ((size_t)(b*64 + (h&3)*16))*NPOS;
  int cr = threadIdx.x >> 4, ts = threadIdx.x & 15;
  float s0 = 0.f, s1 = 0.f;
  #pragma unroll
  for (int p2 = 0; p2 < 16; ++p2) {
    int tt = ts + p2*16;
    float v = src[(size_t)cr*NPOS + t0 + tt];
    ld[tt][cr] = v;
    if (tn < 2) { if (half_t[t0+tt]) s1 += v*v; else s0 += v*v; }
  }
  if (tn < 2) {
    s0 += __shfl_down(s0, 8, 16); s1 += __shfl_down(s1, 8, 16);
    s0 += __shfl_down(s0, 4, 16); s1 += __shfl_down(s1, 4, 16);
    s0 += __shfl_down(s0, 2, 16); s1 += __shfl_down(s1, 2, 16);
    s0 += __shfl_down(s0, 1, 16); s1 += __shfl_down(s1, 1, 16);
    if (ts == 0) {
      float* dn = (tn == 0) ? nq : nk;
      int bh = b*8 + h;
      atomicAdd(&dn[bh*32 + 2*cr],     s0);
      atomicAdd(&dn[bh*32 + 2*cr + 1], s1);
    }
  }
  __syncthreads();
  float* dst = T + ((size_t)blockIdx.y*NPOS + t0)*16;
  int cc = threadIdx.x & 15, tr = threadIdx.x >> 4;
  #pragma unroll
  for (int p2 = 0; p2 < 16; ++p2) {
    int tt = tr + p2*16;
    dst[(size_t)tt*16 + cc] = ld[tt][cc];
  }
}

// ======== gram over sorted columns n, branch-free 4x4 register tiles =============
__global__ __launch_bounds__(256) void k_gramn(const float* __restrict__ T,
        const int* __restrict__ t0n, const int* __restrict__ t1n,
        float* __restrict__ gram, int b) {
  __shared__ float q0s[16][68], q1s[16][68], k0s[16][68], k1s[16][68];
  __shared__ int tl[128];
  __shared__ float red[3][64][16];
  int tid = threadIdx.x;
  int np = tid >> 6, lane = tid & 63;
  int i = lane >> 3, j = lane & 7;
  int h = blockIdx.y;
  const float* Tq = T + (size_t)h*NPOS*16;
  const float* Tk = T + (size_t)(8 + h)*NPOS*16;
  float acc[16];
  #pragma unroll
  for (int z = 0; z < 16; ++z) acc[z] = 0.f;
  for (int it = 0; it < 3; ++it) {
    int n0 = (blockIdx.x*3 + it)*64;
    __syncthreads();
    if (tid < 128) tl[tid] = ((tid < 64) ? t0n[n0 + tid] : t1n[n0 + tid - 64]) * 16;
    __syncthreads();
    for (int e = tid; e < 1024; e += 256) {
      int nn = e >> 4, c2 = e & 15;
      int a0 = tl[nn], a1 = tl[64+nn];
      q0s[c2][nn] = Tq[(size_t)a0 + c2];
      q1s[c2][nn] = Tq[(size_t)a1 + c2];
      k0s[c2][nn] = Tk[(size_t)a0 + c2];
      k1s[c2][nn] = Tk[(size_t)a1 + c2];
    }
    __syncthreads();
    #pragma unroll
    for (int m = 0; m < 4; ++m) {
      int n = m*16 + np*4;
      float4 qA0 = *(const float4*)&q0s[i][n];
      float4 qB0 = *(const float4*)&q0s[i+8][n];
      float4 qA1 = *(const float4*)&q1s[i][n];
      float4 qB1 = *(const float4*)&q1s[i+8][n];
      float4 kA0 = *(const float4*)&k0s[j][n];
      float4 kB0 = *(const float4*)&k0s[j+8][n];
      float4 kA1 = *(const float4*)&k1s[j][n];
      float4 kB1 = *(const float4*)&k1s[j+8][n];
      const float* xa0 = (const float*)&qA0;
      const float* xa1 = (const float*)&qA1;
      const float* xb0 = (const float*)&qB0;
      const float* xb1 = (const float*)&qB1;
      const float* ya0 = (const float*)&kA0;
      const float* ya1 = (const float*)&kA1;
      const float* yb0 = (const float*)&kB0;
      const float* yb1 = (const float*)&kB1;
      #pragma unroll
      for (int nn = 0; nn < 4; ++nn) {
        float xA0 = xa0[nn], xA1 = xa1[nn], xB0 = xb0[nn], xB1 = xb1[nn];
        float yA0 = ya0[nn], yA1 = ya1[nn], yB0 = yb0[nn], yB1 = yb1[nn];
        acc[0]  += xA0*yA0; acc[1]  += xA0*yA1; acc[2]  += xA0*yB0; acc[3]  += xA0*yB1;
        acc[4]  += xA1*yA0; acc[5]  += xA1*yA1; acc[6]  += xA1*yB0; acc[7]  += xA1*yB1;
        acc[8]  += xB0*yA0; acc[9]  += xB0*yA1; acc[10] += xB0*yB0; acc[11] += xB0*yB1;
        acc[12] += xB1*yA0; acc[13] += xB1*yA1; acc[14] += xB1*yB0; acc[15] += xB1*yB1;
      }
    }
  }
  __syncthreads();
  if (np > 0) {
    #pragma unroll
    for (int z = 0; z < 16; ++z) red[np-1][lane][z] = acc[z];
  }
  __syncthreads();
  if (np == 0) {
    float* G = gram + (size_t)(b*8 + h)*1024;
    #pragma unroll
    for (int z = 0; z < 16; ++z) {
      float v = acc[z] + red[0][lane][z] + red[1][lane][z] + red[2][lane][z];
      int qs = z >> 2, ks = z & 3;
      int r  = 2*(i + 8*(qs>>1)) + (qs&1);
      int cl = 2*(j + 8*(ks>>1)) + (ks&1);
      atomicAdd(&G[r*32 + cl], v);
    }
  }
}

// ---------------- softmax1 with cosine normalization + temperature ---------------
__global__ void k_attn(const float* __restrict__ gram, const float* __restrict__ nq,
                       const float* __restrict__ nk, const float* __restrict__ temp,
                       float* __restrict__ attn, int b0) {
  __shared__ float lnk[32];
  int bh = b0*8 + blockIdx.x, h = bh & 7;
  int r = threadIdx.x;
  if (r < 32) lnk[r] = fmaxf(sqrtf(nk[bh*32 + r]), 1e-12f);
  __syncthreads();
  if (r >= 32) return;
  float T = temp[h];
  float nqr = fmaxf(sqrtf(nq[bh*32 + r]), 1e-12f);
  float e[32]; float s = 0.f;
  #pragma unroll
  for (int c = 0; c < 32; ++c) {
    float g = gram[(size_t)bh*1024 + r*32 + c] / (nqr * lnk[c]) * T;
    e[c] = expf(g);
    s += e[c];
  }
  float is = 1.0f / (s + 1.0f);
  #pragma unroll
  for (int c = 0; c < 32; ++c) attn[(size_t)bh*1024 + r*32 + c] = e[c] * is;
}

// ======== O = attn @ V reading transposed Tv (64B lines for t and pt) ============
__global__ __launch_bounds__(256) void k_on(const float* __restrict__ T,
    const float* __restrict__ attn, const int* __restrict__ partner_t,
    const int* __restrict__ half_t, float* __restrict__ O, int b, size_t psz) {
  __shared__ float At[1024];
  int hh = blockIdx.y;
  for (int e = threadIdx.x; e < 1024; e += 256)
    At[e] = attn[(size_t)(b*8 + hh)*1024 + e];
  __syncthreads();
  int t = blockIdx.x*256 + threadIdx.x;
  int f = half_t[t], pt = partner_t[t];
  const float* tv = T + (size_t)(16 + hh)*NPOS*16;
  const float4* va4 = (const float4*)(tv + (size_t)t*16);
  const float4* vb4 = (const float4*)(tv + (size_t)pt*16);
  float w0[16], w1[16];
  #pragma unroll
  for (int dq = 0; dq < 4; ++dq) {
    float4 a = va4[dq], bb = vb4[dq];
    w0[4*dq+0] = f ? bb.x : a.x;  w1[4*dq+0] = f ? a.x : bb.x;
    w0[4*dq+1] = f ? bb.y : a.y;  w1[4*dq+1] = f ? a.y : bb.y;
    w0[4*dq+2] = f ? bb.z : a.z;  w1[4*dq+2] = f ? a.z : bb.z;
    w0[4*dq+3] = f ? bb.w : a.w;  w1[4*dq+3] = f ? a.w : bb.w;
  }
  float* op = O + (size_t)(hh>=4 ? 1:0)*psz + ((size_t)(b*64 + (hh&3)*16))*NPOS;
  #pragma unroll
  for (int c = 0; c < 16; ++c) {
    const float4* Ar = (const float4*)&At[(2*c+f)*32];
    float acc = 0.f;
    #pragma unroll
    for (int d = 0; d < 8; ++d) {
      float4 a4 = Ar[d];
      acc += a4.x*w0[2*d] + a4.y*w1[2*d] + a4.z*w0[2*d+1] + a4.w*w1[2*d+1];
    }
    op[(size_t)c*NPOS + t] = acc;
  }
}

// ---------------- OLD gram + row norms (fallback path, NB<4) ---------------------
__global__ __launch_bounds__(256) void k_gram(const float* __restrict__ planes,
    const int* __restrict__ partner_t, const int* __restrict__ half_t,
    float* __restrict__ gram, float* __restrict__ nq, float* __restrict__ nk,
    int b0, size_t psz) {
  __shared__ float qa[16][65], ka[16][65], kb[16][65];
  __shared__ int ptn[64];
  __shared__ int hf[64];
  int lb = blockIdx.y >> 3, h = blockIdx.y & 7;
  int bh = (b0 + lb)*8 + h;
  const float* qp = planes + (size_t)(h>=4 ? 1:0)*psz + ((size_t)(lb*64 + (h&3)*16))*NPOS;
  const float* kp = planes + (size_t)(2 + (h>=4 ? 1:0))*psz + ((size_t)(lb*64 + (h&3)*16))*NPOS;
  int tc = threadIdx.x & 15, td = threadIdx.x >> 4;
  float a00=0.f,a01=0.f,a10=0.f,a11=0.f, q0=0.f,q1=0.f,k0a=0.f,k1a=0.f;
  for (int it = 0; it < 6; ++it) {
    int t0 = (blockIdx.x*6 + it)*64;
    if (threadIdx.x < 64) {
      ptn[threadIdx.x] = partner_t[t0 + threadIdx.x];
      hf[threadIdx.x]  = half_t[t0 + threadIdx.x];
    }
    __syncthreads();
    for (int e = threadIdx.x; e < 1024; e += 256) {
      int cc = e >> 6, j = e & 63;
      qa[cc][j] = qp[(size_t)cc*NPOS + t0 + j];
      ka[cc][j] = kp[(size_t)cc*NPOS + t0 + j];
      kb[cc][j] = kp[(size_t)cc*NPOS + ptn[j]];
    }
    __syncthreads();
    #pragma unroll 4
    for (int j = 0; j < 64; ++j) {
      float q = qa[tc][j], v1 = ka[td][j], v2 = kb[td][j];
      int f = hf[j];
      float p1 = q*v1, p2 = q*v2;
      if (f) { a11 += p1; a10 += p2; } else { a00 += p1; a01 += p2; }
      if (td == 0) { float qq = q*q; if (f) q1 += qq; else q0 += qq; }
      if (tc == 0) { float kk = v1*v1; if (f) k1a += kk; else k0a += kk; }
    }
    __syncthreads();
  }
  float* G = gram + (size_t)bh*1024;
  atomicAdd(&G[(2*tc+0)*32 + 2*td+0], a00);
  atomicAdd(&G[(2*tc+0)*32 + 2*td+1], a01);
  atomicAdd(&G[(2*tc+1)*32 + 2*td+0], a10);
  atomicAdd(&G[(2*tc+1)*32 + 2*td+1], a11);
  if (td == 0) { atomicAdd(&nq[bh*32 + 2*tc], q0); atomicAdd(&nq[bh*32 + 2*tc+1], q1); }
  if (tc == 0) { atomicAdd(&nk[bh*32 + 2*td], k0a); atomicAdd(&nk[bh*32 + 2*td+1], k1a); }
}

// ---------------- OLD O = attn @ V (fallback path, NB<4) -------------------------
__global__ __launch_bounds__(256) void k_o(const float* __restrict__ planes,
    const float* __restrict__ attn, const int* __restrict__ partner_t,
    const int* __restrict__ half_t, float* __restrict__ O, int b0, size_t psz) {
  __shared__ float At[8][1024];
  int lb = blockIdx.y;
  for (int e = threadIdx.x; e < 8192; e += 256)
    At[e>>10][e&1023] = attn[((size_t)(b0+lb)*8)*1024 + e];
  __syncthreads();
  int t = blockIdx.x*256 + threadIdx.x;
  int f = half_t[t], pt = partner_t[t];
  #pragma unroll 1
  for (int hh = 0; hh < 8; ++hh) {
    const float* vp = planes + (size_t)(4 + (hh>=4 ? 1:0))*psz + ((size_t)(lb*64 + (hh&3)*16))*NPOS;
    float* op = O + (size_t)(hh>=4 ? 1:0)*psz + ((size_t)(lb*64 + (hh&3)*16))*NPOS;
    float w0[16], w1[16];
    #pragma unroll
    for (int d = 0; d < 16; ++d) {
      float va = vp[(size_t)d*NPOS + t];
      float vb = vp[(size_t)d*NPOS + pt];
      w0[d] = f ? vb : va;
      w1[d] = f ? va : vb;
    }
    #pragma unroll
    for (int c = 0; c < 16; ++c) {
      const float4* Ar = (const float4*)&At[hh][(2*c+f)*32];
      float acc = 0.f;
      #pragma unroll
      for (int d = 0; d < 8; ++d) {
        float4 a4 = Ar[d];
        acc += a4.x*w0[2*d] + a4.y*w1[2*d] + a4.z*w0[2*d+1] + a4.w*w1[2*d+1];
      }
      op[(size_t)c*NPOS + t] = acc;
    }
  }
}

// ---------------- inverse column FFT (e^{+}), register-resident, transpose store -
__global__ __launch_bounds__(512) void k_colifft(const float* __restrict__ O,
        float2* __restrict__ IT, size_t psz) {
  __shared__ float Zr[8][264], Zi[8][264];
  __shared__ float tc[258], ts[258];
  int tid = threadIdx.x;
  int wave = tid >> 6, lane = tid & 63;
  int lb = blockIdx.z, c = blockIdx.y;
  int kreal = blockIdx.x*8 + wave;
  int k = (kreal < 129) ? kreal : 128;
  fill_tab<1>(tc, ts, tid);
  const float* pre = O + ((size_t)lb*64 + c)*NPOS + (size_t)k*256;
  const float* pim = pre + psz;
  #pragma unroll
  for (int i = 0; i < 4; ++i) {
    int h = lane + 64*i;
    int r = ZX(rev8(h));
    Zr[wave][r] = pre[h]; Zi[wave][r] = pim[h];
  }
  __syncthreads();   // publish table (covers wave-private Z too)
  float zr[4], zi[4];
  #pragma unroll
  for (int q = 0; q < 4; ++q) {
    zr[q] = Zr[wave][ZX(lane+64*q)]; zi[q] = Zi[wave][ZX(lane+64*q)];
  }
  #pragma unroll
  for (int s = 0; s < 6; ++s) {     // L = 1..32
    int L = 1 << s;
    int kk = lane & (L-1);
    float cs = tc[L+kk], sn = ts[L+kk];
    bool low = (lane & L) != 0;
    bf_shfl(zr[0], zi[0], L, low, cs, sn);
    bf_shfl(zr[1], zi[1], L, low, cs, sn);
    bf_shfl(zr[2], zi[2], L, low, cs, sn);
    bf_shfl(zr[3], zi[3], L, low, cs, sn);
  }
  { float cs = tc[64+lane], sn = ts[64+lane];     // L=64 in-thread
    bf_pair(zr[0], zi[0], zr[1], zi[1], cs, sn);
    bf_pair(zr[2], zi[2], zr[3], zi[3], cs, sn); }
  bf_pair(zr[0], zi[0], zr[2], zi[2], tc[128+lane], ts[128+lane]);   // L=128
  bf_pair(zr[1], zi[1], zr[3], zi[3], tc[192+lane], ts[192+lane]);
  #pragma unroll
  for (int q = 0; q < 4; ++q) {
    Zr[wave][ZX(lane+64*q)] = zr[q]; Zi[wave][ZX(lane+64*q)] = zi[q];
  }
  __syncthreads();   // publish Z across waves (transposed store reads other waves)
  float2* outp = IT + ((size_t)lb*64 + c)*256*WP;
  int k0 = blockIdx.x*8;
  for (int e = tid; e < 2048; e += 512) {
    int hpos = e >> 3, kk2 = e & 7;
    if (k0 + kk2 <= 128) {
      int a = ZX(hpos);
      outp[(size_t)hpos*WP + k0 + kk2] =
        make_float2(Zr[kk2][a]*(1.0f/256.0f), Zi[kk2][a]*(1.0f/256.0f));
    }
  }
}

// ---------------- row irfft: 129 complex -> 256 real, register-resident ----------
__global__ __launch_bounds__(512) void k_rowirfft(const float2* __restrict__ IT,
        float* __restrict__ sp) {
  __shared__ float2 Xl[8][132];
  __shared__ float Zr[8][132], Zi[8][132];
  __shared__ float tc[258], ts[258];
  int tid = threadIdx.x;
  int wave = tid >> 6, lane = tid & 63;
  int lb = blockIdx.z, c = blockIdx.y;
  int h = blockIdx.x*8 + wave;
  fill_tab<1>(tc, ts, tid);
  const float2* row = IT + (((size_t)lb*64 + c)*256 + h)*WP;
  float2 v0 = row[lane];     if (lane == 0) v0.y = 0.f;       // imag of DC dropped
  float2 v1 = row[lane+64];
  Xl[wave][lane] = v0;
  Xl[wave][lane+64] = v1;
  if (lane == 0) { float2 vn = row[128]; vn.y = 0.f; Xl[wave][128] = vn; } // Nyquist
  __syncthreads();   // publish table (Xl is wave-local)
  #pragma unroll
  for (int u = 0; u < 2; ++u) {
    int kk = lane + 64*u;
    float2 Xk = Xl[wave][kk];
    float2 Xm = Xl[wave][128-kk];
    float Ar = Xk.x + Xm.x, Ai = Xk.y - Xm.y;   // X[k]+conj(X[128-k])
    float Br = Xk.x - Xm.x, Bi = Xk.y + Xm.y;   // X[k]-conj(X[128-k])
    float cs = tc[128+kk], sn = ts[128+kk];
    float tr = cs*Br - sn*Bi, ti = cs*Bi + sn*Br;  // e^{+2pi i k/256} * B
    int r = ZX(rev7(kk));
    Zr[wave][r] = Ar - ti; Zi[wave][r] = Ai + tr;
  }
  wsync();
  float z0r = Zr[wave][ZX(lane)],    z0i = Zi[wave][ZX(lane)];
  float z1r = Zr[wave][ZX(lane+64)], z1i = Zi[wave][ZX(lane+64)];
  #pragma unroll
  for (int s = 0; s < 6; ++s) {     // L = 1..32
    int L = 1 << s;
    int kk = lane & (L-1);
    float cs = tc[L+kk], sn = ts[L+kk];
    bool low = (lane & L) != 0;
    bf_shfl(z0r, z0i, L, low, cs, sn);
    bf_shfl(z1r, z1i, L, low, cs, sn);
  }
  bf_pair(z0r, z0i, z1r, z1i, tc[64+lane], ts[64+lane]);   // L=64 in-thread
  float2* orow = (float2*)(sp + (((size_t)lb*64 + c)*256 + h)*256);
  orow[lane]    = make_float2(z0r, z0i);
  orow[lane+64] = make_float2(z1r, z1i);
}

// =================================================================================
extern "C" void kernel_launch(void* const* d_in, const int* in_sizes, int n_in,
                              void* d_out, int out_size, void* d_ws, size_t ws_size,
                              hipStream_t stream) {
  const float* x      = (const float*)d_in[0];
  const float* w_qkv  = (const float*)d_in[1];
  const float* w_dw   = (const float*)d_in[2];
  const float* w_proj = (const float*)d_in[3];
  const float* temp   = (const float*)d_in[4];
  float* out = (float*)d_out;

  char* ws = (char*)d_ws;
  // SMALL region layout (hist/base dead after k_build; t0n/t1n alias them)
  int*   hist = (int*)(ws + 0);        // 65536 B
  int*   base = (int*)(ws + 65536);    // 65536 B
  int*   t0n  = (int*)(ws + 0);        // 66048 B (aliases hist)
  int*   t1n  = (int*)(ws + 66048);    // 66048 B (aliases hist/base tail)
  int*   idx  = (int*)(ws + 132352);   // 132096 B
  int*   inv  = (int*)(ws + 264448);   // 132096 B
  int*   ptn  = (int*)(ws + 396544);   // 132096 B
  int*   hlf  = (int*)(ws + 528640);   // 132096 B
  float* gram = (float*)(ws + 660736); // 131072 B
  float* nq   = (float*)(ws + 791808); // 4096 B
  float* nk   = (float*)(ws + 795904); // 4096 B
  float* attn = (float*)(ws + 800000); // 131072 B -> ends 931072 < 1 MiB

  const size_t SMALL   = 1048576;
  const size_t PLANESB = 50724864;   // 6 * 64 * 33024 * 4 bytes per batch elem
  int NB = 1;
  if (ws_size >= SMALL + 2*PLANESB) NB = 2;
  if (ws_size >= SMALL + 4*PLANESB) NB = 4;

  float*  P   = (float*)(ws + SMALL);
  size_t  psz = (size_t)NB * 64 * NPOS;   // one plane, in floats
  float*  O   = P;                        // aliases planes 0,1 (Q, dead after gram/t16)
  float2* IT  = (float2*)(P + 2*psz);     // aliases planes 2,3 (K, dead after gram)
  float*  sp  = P + 4*psz;                // aliases planes 4,5 (V, dead after k_o/t16)

  // permutation maps (recomputed every call; ws is re-poisoned by harness)
  k_hist <<<dim3(64), dim3(256), 0, stream>>>(hist);
  k_scan <<<dim3(1),  dim3(512), 0, stream>>>(hist, base);
  k_build<<<dim3(64), dim3(256), 0, stream>>>(base, idx, inv);
  k_maps <<<dim3(129),dim3(256), 0, stream>>>(idx, inv, ptn, hlf);
  k_maps2<<<dim3(65), dim3(256), 0, stream>>>(idx, t0n, t1n);   // overwrites hist/base (dead)
  k_zero <<<dim3(136),dim3(256), 0, stream>>>(gram);

  if (NB == 4) {
    // ---- fast path: single pass, attention uses d_out as transpose scratch ----
    float* tmpb = out;   // staging; dead after forward
    for (int tn = 0; tn < 3; ++tn) {
      k_conv64  <<<dim3(256, 4), dim3(256), 0, stream>>>(x, w_qkv + (size_t)tn*64*64, tmpb);
      k_dwrowfft<<<dim3(32, 64, 4), dim3(512), 0, stream>>>(tmpb, w_dw, P, tn, psz);
      k_colfft  <<<dim3(17, 64, 4), dim3(512), 0, stream>>>(P, tn, psz);
    }
    float* T = out;   // 3 tensors * 8 heads * NPOS * 16 floats = 50.7 MB <= out (67.1 MB)
    for (int b = 0; b < 4; ++b) {
      k_t16  <<<dim3(129, 24), dim3(256), 0, stream>>>(P, T, hlf, nq, nk, b, psz);
      k_gramn<<<dim3(86, 8),   dim3(256), 0, stream>>>(T, t0n, t1n, gram, b);
      k_attn <<<dim3(8),       dim3(64),  0, stream>>>(gram, nq, nk, temp, attn, b);
      k_on   <<<dim3(129, 8),  dim3(256), 0, stream>>>(T, attn, ptn, hlf, O, b, psz);
    }
    k_colifft <<<dim3(17, 64, 4), dim3(512), 0, stream>>>(O, IT, psz);
    k_rowirfft<<<dim3(32, 64, 4), dim3(512), 0, stream>>>(IT, sp);
    k_conv64  <<<dim3(256, 4), dim3(256), 0, stream>>>(sp, w_proj, out);
  } else {
    // ---- fallback: previous verified path ----
    for (int b0 = 0; b0 < 4; b0 += NB) {
      float* tmpb = out + (size_t)b0*64*HW;
      for (int tn = 0; tn < 3; ++tn) {
        k_conv64  <<<dim3(256, NB), dim3(256), 0, stream>>>(
            x + (size_t)b0*64*HW, w_qkv + (size_t)tn*64*64, tmpb);
        k_dwrowfft<<<dim3(32, 64, NB), dim3(512), 0, stream>>>(tmpb, w_dw, P, tn, psz);
        k_colfft  <<<dim3(17, 64, NB), dim3(512), 0, stream>>>(P, tn, psz);
      }
      k_gram<<<dim3(86, NB*8), dim3(256), 0, stream>>>(P, ptn, hlf, gram, nq, nk, b0, psz);
      k_attn<<<dim3(NB*8), dim3(64), 0, stream>>>(gram, nq, nk, temp, attn, b0);
      k_o   <<<dim3(129, NB), dim3(256), 0, stream>>>(P, attn, ptn, hlf, O, b0, psz);
      k_colifft <<<dim3(17, 64, NB), dim3(512), 0, stream>>>(O, IT, psz);
      k_rowirfft<<<dim3(32, 64, NB), dim3(512), 0, stream>>>(IT, sp);
      k_conv64  <<<dim3(256, NB), dim3(256), 0, stream>>>(sp, w_proj, out + (size_t)b0*64*HW);
    }
  }
}